// Round 10
// baseline (495.160 us; speedup 1.0000x reference)
//
#include <hip/hip_runtime.h>
#include <cmath>
#include <cstdint>

// ---------------------------------------------------------------------------
// DependencyTreeLSTM (R10).  Lesson history:
//  R1 persistent grid-barrier: XCD L2 invalidates -> 2.8x regression.
//  R2 fused level kernel: 256-block grid cap -> latency-bound.
//  R3-R6: GEMMs invariant ~40us: UNCOALESCED STAGING was the shared defect.
//  R7: k-chunk-major global layouts (coalesced global_load_lds): 652->513.
//  R8: ZW hoist (X-half gates to prologue) + coalesced fp: 513->481.
//  R9: zx_all 128x128 tile: 78->74us only; MfmaUtil stuck 22% -> zx_all is
//     write-stream-bound (123MB ZW), NOT MFMA-bound.  Level loop = 343us
//     (28.6us/level) vs ~9us/level floor -> dispatch structure is the cost.
//  R10: level loop 3 -> 2 dispatches:
//   A: fp || reduceHT fused (block-range split; both depend only on lev-1
//      state, disjoint writes).  reduceHT = pure h child-sum from Hk.
//   B: zgemm2 absorbs SC: per-block epilogue gathers its own 64x32 slice
//      (unconditional loads + mask-guarded math).  Kills SCb round-trip
//      (5.2MB w + r / level) and the Hbf row-major H copy.  C ping-pongs.
// ---------------------------------------------------------------------------

#define NN    4096
#define HH    300
#define KK    8
#define LVLS  12
#define KP    320
#define MTOT  49152   // 12*4096 rows in Xall
#define NW    1280    // ZW columns: [wf|wi|wo|wu]

typedef __bf16  bf16x8 __attribute__((ext_vector_type(8)));
typedef float   f32x4  __attribute__((ext_vector_type(4)));

#define GAS __attribute__((address_space(1)))
#define LAS __attribute__((address_space(3)))

__device__ __forceinline__ float sigmoidf_(float x) {
    return 1.0f / (1.0f + expf(-x));
}
__device__ __forceinline__ ushort f2bf(float f) {   // f32 -> bf16, RNE
    union { float f; uint32_t u; } v; v.f = f;
    return (ushort)((v.u + 0x7fffu + ((v.u >> 16) & 1u)) >> 16);
}
__device__ __forceinline__ float bf2f(ushort u) {
    union { uint32_t u; float f; } v; v.u = ((uint32_t)u) << 16;
    return v.f;
}

// ---------------------------------------------------------------------------
// pack (blocks [0,3527)) + stage X' (blocks [3527, 11207)).
// Layouts (k-chunk-major = [k/8][cols][8], coalesced staging):
//   W4  [40][1280][8]  rows: 0-319 wf, 320-639 wi, 640-959 wo, 960-1279 wu
//   Uf' [40][320][8];  WzU [3][40][320][8];  Xall'[40][49152][8]
//   BZ[3][320]=b_w+b_u, Bwf[320], BUF[320];  H' k-pads zeroed once.
// ---------------------------------------------------------------------------
__global__ __launch_bounds__(256)
void pack_and_stage(
    const float* __restrict__ wi, const float* __restrict__ bwi,
    const float* __restrict__ ui, const float* __restrict__ bui,
    const float* __restrict__ wf, const float* __restrict__ bwf,
    const float* __restrict__ uf, const float* __restrict__ buf_,
    const float* __restrict__ wo, const float* __restrict__ bwo,
    const float* __restrict__ uo, const float* __restrict__ buo,
    const float* __restrict__ wu, const float* __restrict__ bwu,
    const float* __restrict__ uu, const float* __restrict__ buu,
    ushort* __restrict__ W4, ushort* __restrict__ Ufp, ushort* __restrict__ WzU,
    float* __restrict__ BZ, float* __restrict__ Bwf, float* __restrict__ BUF,
    ushort* __restrict__ Hk,
    const int* __restrict__ word_ids, const float* __restrict__ emb,
    ushort* __restrict__ X)
{
    const int b = blockIdx.x;
    if (b >= 3527) {                                     // ---- stage X' ----
        int idx = (b - 3527) * 256 + threadIdx.x;        // 40 * 49152
        int kb = idx / MTOT, row = idx % MTOT;
        const int k0 = kb * 8;
        ushort o[8];
        if (kb < 37) {
            const float4* p = reinterpret_cast<const float4*>(
                emb + (size_t)word_ids[row] * 300 + k0);
            float4 v0 = p[0], v1 = p[1];
            o[0] = f2bf(v0.x); o[1] = f2bf(v0.y); o[2] = f2bf(v0.z); o[3] = f2bf(v0.w);
            o[4] = f2bf(v1.x); o[5] = f2bf(v1.y); o[6] = f2bf(v1.z); o[7] = f2bf(v1.w);
        } else if (kb == 37) {
            const float4 v0 = *reinterpret_cast<const float4*>(
                emb + (size_t)word_ids[row] * 300 + k0);
            o[0] = f2bf(v0.x); o[1] = f2bf(v0.y); o[2] = f2bf(v0.z); o[3] = f2bf(v0.w);
            o[4] = o[5] = o[6] = o[7] = 0;
        } else {
            o[0] = o[1] = o[2] = o[3] = o[4] = o[5] = o[6] = o[7] = 0;
        }
        ushort* dst = X + ((size_t)kb * MTOT + row) * 8;
        ushort4 a; a.x = o[0]; a.y = o[1]; a.z = o[2]; a.w = o[3];
        ushort4 c; c.x = o[4]; c.y = o[5]; c.z = o[6]; c.w = o[7];
        *reinterpret_cast<ushort4*>(dst)     = a;
        *reinterpret_cast<ushort4*>(dst + 4) = c;
        return;
    }
    int t = b * 256 + threadIdx.x;                       // ---- pack part ----
    if (t < 409600) {                                    // W4 [40][1280][8]
        int gate = t / 102400, rem = t % 102400;
        int r = rem / 320, k = rem % 320;
        const float* W = (gate == 0) ? wf : (gate == 1) ? wi
                       : (gate == 2) ? wo : wu;
        float v = (r < 300 && k < 300) ? W[r * 300 + k] : 0.f;
        W4[((size_t)(k >> 3) * NW + gate * 320 + r) * 8 + (k & 7)] = f2bf(v);
    } else if (t < 512000) {                             // Uf' [40][320][8]
        int x = t - 409600, r = x / 320, k = x % 320;
        Ufp[((size_t)(k >> 3) * KP + r) * 8 + (k & 7)] =
            f2bf((r < 300 && k < 300) ? uf[r * 300 + k] : 0.f);
    } else if (t < 819200) {                             // WzU [3][40][320][8]
        int x = t - 512000;
        int g = x / 102400, rem = x % 102400;
        int r = rem / 320, k = rem % 320;
        const float* U = (g == 0) ? ui : (g == 1) ? uo : uu;
        WzU[(((size_t)g * 40 + (k >> 3)) * KP + r) * 8 + (k & 7)] =
            f2bf((r < 300 && k < 300) ? U[r * 300 + k] : 0.f);
    } else if (t < 820160) {                             // BZ [3][320]
        int x = t - 819200, g = x / KP, r = x % KP;
        const float* bw = (g == 0) ? bwi : (g == 1) ? bwo : bwu;
        const float* bu = (g == 0) ? bui : (g == 1) ? buo : buu;
        BZ[x] = (r < 300) ? bw[r] + bu[r] : 0.f;
    } else if (t < 820480) {                             // Bwf
        int r = t - 820160;
        Bwf[r] = (r < 300) ? bwf[r] : 0.f;
    } else if (t < 820800) {                             // BUF
        int r = t - 820480;
        BUF[r] = (r < 300) ? buf_[r] : 0.f;
    } else if (t < 902720) {                             // H' k-pads -> 0
        int x = t - 820800;                              // 4096 * 20
        int row = x / 20, pe = x % 20;
        int k = 300 + pe;
        Hk[((size_t)(k >> 3) * NN + row) * 8 + (k & 7)] = 0;
    }
}

// ---------------------------------------------------------------------------
// ZW = X_all @ W4^T (+b_wf on cols<320) -> bf16 [49152][1280].
// Grid 3840, 128x128 tile, BK=32, dbuf + counted vmcnt(4).  (Write-stream
// bound per R9 -- frozen this round.)
// ---------------------------------------------------------------------------
__global__ __launch_bounds__(256)
void zx_all_kernel(const ushort* __restrict__ Xp, const ushort* __restrict__ W4,
                   const float* __restrict__ Bwf, ushort* __restrict__ ZW)
{
    __shared__ __attribute__((aligned(16))) ushort As[2][4][128][8];  // 16 KB
    __shared__ __attribute__((aligned(16))) ushort Bs[2][4][128][8];  // 16 KB

    const int b  = blockIdx.x;
    const int bj = (b % 8) * 480 + b / 8;         // bijective (3840 % 8 == 0)
    const int m0 = (bj / 10) * 128, n0 = (bj % 10) * 128;

    const int t = threadIdx.x, l = t & 63, w = t >> 6;
    const int m_off = (w >> 1) * 64, n_off = (w & 1) * 64;
    const int kq = l >> 4, lr = l & 15;

    f32x4 acc[4][4] = {};

    auto STAGE = [&](int buf, int s) {
        #pragma unroll
        for (int c = 0; c < 2; ++c) {             // A: 512 slots, 2/thread
            const int slot = t + 256 * c;
            const int kb = slot >> 7, row = slot & 127;
            const ushort* src = Xp + ((size_t)(s * 4 + kb) * MTOT + m0 + row) * 8;
            __builtin_amdgcn_global_load_lds((const GAS void*)src,
                (LAS void*)&As[buf][kb][row][0], 16, 0, 0);
        }
        #pragma unroll
        for (int c = 0; c < 2; ++c) {             // B: 512 slots, 2/thread
            const int slot = t + 256 * c;
            const int kb = slot >> 7, row = slot & 127;
            const ushort* src = W4 + ((size_t)(s * 4 + kb) * NW + n0 + row) * 8;
            __builtin_amdgcn_global_load_lds((const GAS void*)src,
                (LAS void*)&Bs[buf][kb][row][0], 16, 0, 0);
        }
    };
    auto COMPUTE = [&](int buf) {
        bf16x8 af[4], bfr[4];
        #pragma unroll
        for (int mi = 0; mi < 4; ++mi)
            af[mi] = *reinterpret_cast<const bf16x8*>(
                &As[buf][kq][m_off + mi * 16 + lr][0]);
        #pragma unroll
        for (int ni = 0; ni < 4; ++ni)
            bfr[ni] = *reinterpret_cast<const bf16x8*>(
                &Bs[buf][kq][n_off + ni * 16 + lr][0]);
        #pragma unroll
        for (int mi = 0; mi < 4; ++mi)
            #pragma unroll
            for (int ni = 0; ni < 4; ++ni)
                acc[mi][ni] = __builtin_amdgcn_mfma_f32_16x16x32_bf16(
                    af[mi], bfr[ni], acc[mi][ni], 0, 0, 0);
    };

    STAGE(0, 0);
    #pragma unroll
    for (int s = 0; s < 9; ++s) {
        STAGE((s + 1) & 1, s + 1);                // 4 loads in flight
        asm volatile("s_waitcnt vmcnt(4)" ::: "memory");
        __builtin_amdgcn_s_barrier();
        COMPUTE(s & 1);
        __builtin_amdgcn_s_barrier();
    }
    asm volatile("s_waitcnt vmcnt(0)" ::: "memory");
    __builtin_amdgcn_s_barrier();
    COMPUTE(1);                                   // step 9 -> buf 1

    const int col = l & 15, r0 = (l >> 4) * 4;
    #pragma unroll
    for (int mi = 0; mi < 4; ++mi) {
        #pragma unroll
        for (int ni = 0; ni < 4; ++ni) {
            const int gn = n0 + n_off + ni * 16 + col;
            const float bb = (gn < 320) ? Bwf[gn] : 0.f;
            #pragma unroll
            for (int r = 0; r < 4; ++r) {
                const int gm = m0 + m_off + mi * 16 + r0 + r;
                ZW[(size_t)gm * NW + gn] = f2bf(acc[mi][ni][r] + bb);
            }
        }
    }
}

// ---------------------------------------------------------------------------
// Dispatch A: fp (blocks [0,640)) || reduceHT (blocks [640,1664)).
// Both read only level-1 state (Hk); writes disjoint (FP vs HTp).
//  fp:       FP = H @ u_f^T + b_uf (coalesced dbuf GEMM, unchanged body).
//  reduceHT: HT[n] = sum_k m*h_child  (4 nodes/block, 1 node/wave; lane l
//            covers chunks l and l+64(<75); lanes 11-15 zero pads 75-79).
// ---------------------------------------------------------------------------
__global__ __launch_bounds__(256)
void fp_ht_kernel(const ushort* __restrict__ Hk, const ushort* __restrict__ Ufp,
                  const float* __restrict__ BUFb, ushort* __restrict__ FP,
                  const int* __restrict__ cidx, const float* __restrict__ cmask,
                  ushort* __restrict__ HTp, int fp_on)
{
    __shared__ __attribute__((aligned(16))) ushort As[2][8][64][8];   // 16 KB
    __shared__ __attribute__((aligned(16))) ushort Bs[2][8][32][8];   //  8 KB
    __shared__ int   ch4[4][KK];
    __shared__ float mk4[4][KK];

    const int b = blockIdx.x;
    const int t = threadIdx.x, w = t >> 6, l = t & 63;

    if (b < 640) {                                // ================= fp ====
        if (!fp_on) return;
        const int bj = (b % 8) * 80 + b / 8;
        const int m0 = (bj / 10) * 64, j0 = (bj % 10) * 32;
        const int kq = l >> 4, lr = l & 15;
        const int m_off = (w >> 1) * 32, j_off = (w & 1) * 16;

        f32x4 acc[2] = {};

        auto STAGE = [&](int buf, int s) {
            #pragma unroll
            for (int c = 0; c < 2; ++c) {         // A: 512 slots, 2/thread
                const int slot = t + 256 * c;
                const int kb = slot >> 6, row = slot & 63;
                const ushort* src = Hk + ((size_t)(s * 8 + kb) * NN + m0 + row) * 8;
                __builtin_amdgcn_global_load_lds((const GAS void*)src,
                    (LAS void*)&As[buf][kb][row][0], 16, 0, 0);
            }
            {                                     // B: 256 slots, 1/thread
                const int kb = t >> 5, row = t & 31;
                const ushort* src = Ufp + ((size_t)(s * 8 + kb) * KP + j0 + row) * 8;
                __builtin_amdgcn_global_load_lds((const GAS void*)src,
                    (LAS void*)&Bs[buf][kb][row][0], 16, 0, 0);
            }
        };
        auto COMPUTE = [&](int buf) {
            #pragma unroll
            for (int kk = 0; kk < 2; ++kk) {
                const int kc = kk * 4 + kq;
                bf16x8 af[2], bf;
                #pragma unroll
                for (int mi = 0; mi < 2; ++mi)
                    af[mi] = *reinterpret_cast<const bf16x8*>(
                        &As[buf][kc][m_off + mi * 16 + lr][0]);
                bf = *reinterpret_cast<const bf16x8*>(
                        &Bs[buf][kc][j_off + lr][0]);
                #pragma unroll
                for (int mi = 0; mi < 2; ++mi)
                    acc[mi] = __builtin_amdgcn_mfma_f32_16x16x32_bf16(
                        af[mi], bf, acc[mi], 0, 0, 0);
            }
        };

        STAGE(0, 0);
        #pragma unroll
        for (int s = 0; s < 4; ++s) {
            STAGE((s + 1) & 1, s + 1);            // 3 loads in flight
            asm volatile("s_waitcnt vmcnt(3)" ::: "memory");
            __builtin_amdgcn_s_barrier();
            COMPUTE(s & 1);
            __builtin_amdgcn_s_barrier();
        }
        asm volatile("s_waitcnt vmcnt(0)" ::: "memory");
        __builtin_amdgcn_s_barrier();
        COMPUTE(0);                               // step 4 -> buf 0

        const int col = l & 15, r0 = (l >> 4) * 4;
        const int gn = j0 + j_off + col;
        if (gn < 300) {
            const float bb = BUFb[gn];
            #pragma unroll
            for (int mi = 0; mi < 2; ++mi)
                #pragma unroll
                for (int r = 0; r < 4; ++r)
                    FP[(size_t)(m0 + m_off + mi * 16 + r0 + r) * KP + gn] =
                        f2bf(acc[mi][r] + bb);
        }
        return;
    }

    // ================================ reduceHT ===========================
    const int bid = b - 640;                      // 0..1023
    const int n = bid * 4 + w;                    // 1 node / wave
    if (l < KK) {
        ch4[w][l] = cidx[n * KK + l];
        mk4[w][l] = cmask[n * KK + l];
    }
    __syncthreads();

    const bool two = (l < 11);                    // chunks 64..74
    const int cA = l, cB = l + 64;

    // branchless prefetch (indices always valid; garbage masked in math)
    ushort4 hA[KK], hB[KK];
    #pragma unroll
    for (int k = 0; k < KK; ++k) {
        const size_t cr = (size_t)ch4[w][k];
        hA[k] = *reinterpret_cast<const ushort4*>(
            &Hk[((size_t)(cA >> 1) * NN + cr) * 8 + (cA & 1) * 4]);
        if (two)
            hB[k] = *reinterpret_cast<const ushort4*>(
                &Hk[((size_t)(cB >> 1) * NN + cr) * 8 + (cB & 1) * 4]);
    }
    float ha[4] = {0.f,0.f,0.f,0.f}, hb[4] = {0.f,0.f,0.f,0.f};
    #pragma unroll
    for (int k = 0; k < KK; ++k) {
        const float m = mk4[w][k];
        if (m != 0.f) {
            ha[0] += m * bf2f(hA[k].x); ha[1] += m * bf2f(hA[k].y);
            ha[2] += m * bf2f(hA[k].z); ha[3] += m * bf2f(hA[k].w);
            if (two) {
                hb[0] += m * bf2f(hB[k].x); hb[1] += m * bf2f(hB[k].y);
                hb[2] += m * bf2f(hB[k].z); hb[3] += m * bf2f(hB[k].w);
            }
        }
    }
    {
        ushort4 o; o.x = f2bf(ha[0]); o.y = f2bf(ha[1]);
        o.z = f2bf(ha[2]); o.w = f2bf(ha[3]);
        *reinterpret_cast<ushort4*>(
            &HTp[((size_t)(cA >> 1) * NN + n) * 8 + (cA & 1) * 4]) = o;
    }
    if (two) {
        ushort4 o; o.x = f2bf(hb[0]); o.y = f2bf(hb[1]);
        o.z = f2bf(hb[2]); o.w = f2bf(hb[3]);
        *reinterpret_cast<ushort4*>(
            &HTp[((size_t)(cB >> 1) * NN + n) * 8 + (cB & 1) * 4]) = o;
    }
    if (l >= 11 && l < 16) {                      // zero pad chunks 75..79
        const int c = 64 + l;
        ushort4 z; z.x = z.y = z.z = z.w = 0;
        *reinterpret_cast<ushort4*>(
            &HTp[((size_t)(c >> 1) * NN + n) * 8 + (c & 1) * 4]) = z;
    }
}

// ---------------------------------------------------------------------------
// Dispatch B: zgemm2 = HT-half gates GEMM (K=320, dbuf, counted vmcnt(5))
// + in-epilogue SC gather (own 64x32 slice: 8 children x (FP 2B + C 4B),
// unconditional loads, mask-guarded math) + X-half addend from ZW + cell
// update.  Writes C (ping-pong) and Hk k-major.  Child meta prefetched to
// registers BEFORE the first STAGE (oldest-first vmcnt drain keeps the
// counted waits sound), parked in LDS after the K-loop.
// ---------------------------------------------------------------------------
__global__ __launch_bounds__(256)
void zgemm2(const ushort* __restrict__ HTp, const ushort* __restrict__ WzU,
            const float* __restrict__ BZ, const ushort* __restrict__ ZWlev,
            const ushort* __restrict__ FPb, const float* __restrict__ Cprev,
            const int* __restrict__ cidx, const float* __restrict__ cmask,
            float* __restrict__ cdst, ushort* __restrict__ Hk,
            float* __restrict__ hdst)
{
    __shared__ __attribute__((aligned(16))) ushort As[2][8][64][8];    // 16 KB
    __shared__ __attribute__((aligned(16))) ushort Bs[2][3][8][32][8]; // 24 KB
    __shared__ int   ciL[64][KK];                                      //  2 KB
    __shared__ float mkL[64][KK];                                      //  2 KB

    const int b  = blockIdx.x;
    const int bj = (b % 8) * 80 + b / 8;          // bijective (640 % 8 == 0)
    const int m0 = (bj / 10) * 64, j0 = (bj % 10) * 32;

    const int t = threadIdx.x, w = t >> 6, l = t & 63;
    const int kq = l >> 4, lr = l & 15;
    const int m_off = (w >> 1) * 32, j_off = (w & 1) * 16;

    // child-meta register prefetch (issued before first STAGE; see header)
    const int e0 = t * 2, e1 = e0 + 1;
    const int   ciA = cidx [(m0 + (e0 >> 3)) * KK + (e0 & 7)];
    const float mkA = cmask[(m0 + (e0 >> 3)) * KK + (e0 & 7)];
    const int   ciB = cidx [(m0 + (e1 >> 3)) * KK + (e1 & 7)];
    const float mkB = cmask[(m0 + (e1 >> 3)) * KK + (e1 & 7)];

    f32x4 acc[3][2] = {};

    auto STAGE = [&](int buf, int s) {
        #pragma unroll
        for (int c = 0; c < 2; ++c) {             // A: 512 slots, 2/thread
            const int slot = t + 256 * c;
            const int kb = slot >> 6, row = slot & 63;
            const ushort* src = HTp + ((size_t)(s * 8 + kb) * NN + m0 + row) * 8;
            __builtin_amdgcn_global_load_lds((const GAS void*)src,
                (LAS void*)&As[buf][kb][row][0], 16, 0, 0);
        }
        #pragma unroll
        for (int c = 0; c < 3; ++c) {             // B: 768 slots, 3/thread
            const int slot = t + 256 * c;
            const int g = slot >> 8, rem = slot & 255;
            const int kb = rem >> 5, row = rem & 31;
            const ushort* src = WzU +
                (((size_t)g * 40 + s * 8 + kb) * KP + j0 + row) * 8;
            __builtin_amdgcn_global_load_lds((const GAS void*)src,
                (LAS void*)&Bs[buf][g][kb][row][0], 16, 0, 0);
        }
    };
    auto COMPUTE = [&](int buf) {
        #pragma unroll
        for (int kk = 0; kk < 2; ++kk) {
            const int kc = kk * 4 + kq;
            bf16x8 af[2], bfr[3];
            #pragma unroll
            for (int mi = 0; mi < 2; ++mi)
                af[mi] = *reinterpret_cast<const bf16x8*>(
                    &As[buf][kc][m_off + mi * 16 + lr][0]);
            #pragma unroll
            for (int g = 0; g < 3; ++g)
                bfr[g] = *reinterpret_cast<const bf16x8*>(
                    &Bs[buf][g][kc][j_off + lr][0]);
            #pragma unroll
            for (int g = 0; g < 3; ++g)
                #pragma unroll
                for (int mi = 0; mi < 2; ++mi)
                    acc[g][mi] = __builtin_amdgcn_mfma_f32_16x16x32_bf16(
                        af[mi], bfr[g], acc[g][mi], 0, 0, 0);
        }
    };

    STAGE(0, 0);
    #pragma unroll
    for (int s = 0; s < 4; ++s) {
        STAGE((s + 1) & 1, s + 1);                // 5 loads in flight
        asm volatile("s_waitcnt vmcnt(5)" ::: "memory");
        __builtin_amdgcn_s_barrier();
        COMPUTE(s & 1);
        __builtin_amdgcn_s_barrier();
    }
    asm volatile("s_waitcnt vmcnt(0)" ::: "memory");
    __builtin_amdgcn_s_barrier();
    COMPUTE(0);                                   // step 4 -> buf 0

    // ---- park child meta in LDS, sync, then fused epilogue --------------
    ciL[e0 >> 3][e0 & 7] = ciA;  mkL[e0 >> 3][e0 & 7] = mkA;
    ciL[e1 >> 3][e1 & 7] = ciB;  mkL[e1 >> 3][e1 & 7] = mkB;
    __syncthreads();

    const int col = l & 15, r0 = (l >> 4) * 4;
    const int gn = j0 + j_off + col;
    if (gn < 300) {
        const float bi_ = BZ[gn], bo_ = BZ[KP + gn], bu_ = BZ[2 * KP + gn];
        #pragma unroll
        for (int mi = 0; mi < 2; ++mi) {
            #pragma unroll
            for (int r = 0; r < 4; ++r) {
                const int ridx = m_off + mi * 16 + r0 + r;   // 0..63 local
                const int gm = m0 + ridx;
                const size_t zrow = (size_t)gm * NW;
                const float wx = bf2f(ZWlev[zrow + gn]);
                const float zi = bf2f(ZWlev[zrow + 320 + gn]);
                const float zo = bf2f(ZWlev[zrow + 640 + gn]);
                const float zu = bf2f(ZWlev[zrow + 960 + gn]);
                // branchless prefetch of all 8 children (garbage masked)
                float fpv[KK], ccv[KK], mv[KK];
                #pragma unroll
                for (int k = 0; k < KK; ++k) {
                    const size_t c = (size_t)ciL[ridx][k];
                    mv[k]  = mkL[ridx][k];
                    fpv[k] = bf2f(FPb[c * KP + gn]);
                    ccv[k] = Cprev[c * HH + gn];
                }
                float sc = 0.f;
                #pragma unroll
                for (int k = 0; k < KK; ++k)
                    if (mv[k] != 0.f)
                        sc += mv[k] * sigmoidf_(wx + fpv[k]) * ccv[k];
                const float ig = sigmoidf_(acc[0][mi][r] + zi + bi_);
                const float og = sigmoidf_(acc[1][mi][r] + zo + bo_);
                const float ug = tanhf   (acc[2][mi][r] + zu + bu_);
                const float c_ = ig * ug + sc;
                const float hv = og * tanhf(c_);
                cdst[(size_t)gm * HH + gn] = c_;
                Hk[((size_t)(gn >> 3) * NN + gm) * 8 + (gn & 7)] = f2bf(hv);
                if (hdst) hdst[(size_t)gm * HH + gn] = hv;
            }
        }
    }
}

// ---------------------------------------------------------------------------
extern "C" void kernel_launch(void* const* d_in, const int* in_sizes, int n_in,
                              void* d_out, int out_size, void* d_ws, size_t ws_size,
                              hipStream_t stream)
{
    const int*   word_ids   = (const int*)  d_in[0];
    const int*   child_idx  = (const int*)  d_in[1];
    const float* child_mask = (const float*)d_in[2];
    const float* emb        = (const float*)d_in[3];
    const float* w_i  = (const float*)d_in[4];  const float* b_wi = (const float*)d_in[5];
    const float* u_i  = (const float*)d_in[6];  const float* b_ui = (const float*)d_in[7];
    const float* w_f  = (const float*)d_in[8];  const float* b_wf = (const float*)d_in[9];
    const float* u_f  = (const float*)d_in[10]; const float* b_uf = (const float*)d_in[11];
    const float* w_o  = (const float*)d_in[12]; const float* b_wo = (const float*)d_in[13];
    const float* u_o  = (const float*)d_in[14]; const float* b_uo = (const float*)d_in[15];
    const float* w_u  = (const float*)d_in[16]; const float* b_wu = (const float*)d_in[17];
    const float* u_u  = (const float*)d_in[18]; const float* b_uu = (const float*)d_in[19];

    uint8_t* ws = (uint8_t*)d_ws;
    size_t off = 0;
    auto alloc = [&](size_t bytes) {
        uint8_t* p = ws + off;
        off += (bytes + 255) & ~(size_t)255;
        return p;
    };
    ushort* W4    = (ushort*)alloc((size_t)40 * NW * 8 * 2);      // k-major
    ushort* Ufp   = (ushort*)alloc((size_t)40 * KP * 8 * 2);      // k-major
    ushort* WzU   = (ushort*)alloc((size_t)3 * 40 * KP * 8 * 2);  // k-major
    ushort* Xall  = (ushort*)alloc((size_t)40 * MTOT * 8 * 2);    // k-major
    ushort* ZW    = (ushort*)alloc((size_t)MTOT * NW * 2);        // row-major
    ushort* FPbf  = (ushort*)alloc((size_t)NN * KP * 2);          // row-major
    ushort* HTp   = (ushort*)alloc((size_t)40 * NN * 8 * 2);      // k-major
    ushort* Hk    = (ushort*)alloc((size_t)40 * NN * 8 * 2);      // k-major
    float*  Cb0   = (float*) alloc((size_t)NN * HH * 4);
    float*  Cb1   = (float*) alloc((size_t)NN * HH * 4);
    float*  BZ    = (float*) alloc(3 * KP * 4);
    float*  Bwf   = (float*) alloc(KP * 4);
    float*  BUFb  = (float*) alloc(KP * 4);
    float*  Cb[2] = { Cb0, Cb1 };

    pack_and_stage<<<11207, 256, 0, stream>>>(
        w_i, b_wi, u_i, b_ui, w_f, b_wf, u_f, b_uf,
        w_o, b_wo, u_o, b_uo, w_u, b_wu, u_u, b_uu,
        W4, Ufp, WzU, BZ, Bwf, BUFb, Hk,
        word_ids, emb, Xall);
    zx_all_kernel<<<3840, 256, 0, stream>>>(Xall, W4, Bwf, ZW);

    float* h_final = (float*)d_out;
    float* c_final = (float*)d_out + (size_t)NN * HH;

    int cur = 0;
    for (int lev = 0; lev < LVLS; ++lev) {
        const int*    cidx  = child_idx  + (size_t)lev * NN * KK;
        const float*  cmask = child_mask + (size_t)lev * NN * KK;
        const ushort* ZWlev = ZW + (size_t)lev * NN * NW;
        const bool last = (lev == LVLS - 1);

        fp_ht_kernel<<<1664, 256, 0, stream>>>(
            Hk, Ufp, BUFb, FPbf, cidx, cmask, HTp, lev > 0 ? 1 : 0);
        zgemm2<<<640, 256, 0, stream>>>(
            HTp, WzU, BZ, ZWlev, FPbf, Cb[cur], cidx, cmask,
            last ? c_final : Cb[cur ^ 1], Hk,
            last ? h_final : nullptr);
        cur ^= 1;
    }
}

// Round 13
// 475.147 us; speedup vs baseline: 1.0421x; 1.0421x over previous
//
#include <hip/hip_runtime.h>
#include <cmath>
#include <cstdint>

// ---------------------------------------------------------------------------
// DependencyTreeLSTM (R13 = R9 verbatim revert; best verified: 477.5 us).
// Session ledger: 629 -> 477 us.
//  R7: k-chunk-major global layouts -> coalesced global_load_lds (-139us).
//  R8: ZW hoist (X-half of all 4 gate GEMMs to prologue) + coalesced fp (-32).
//  R9: zx_all 128x128 tile (-4).
// Refuted/failed levers (do not retry):
//  - persistent kernel + software grid barrier (R1: XCD L2 invalidates, 2.8x).
//  - one fused kernel per level (R2: 256-block grid cap, latency-bound).
//  - register-direct fragment loads for skinny GEMMs (R3: VGPR-bound MLP).
//  - BK scaling / counted-vmcnt pipelining alone (R4-R6: staging was
//    uncoalesced -- THAT was the defect, fixed in R7).
//  - 2-dispatch level loop w/ scalar SC gather in zgemm epilogue (R10: +18us).
//  - LDS-staged zx_all output tile, aliased (R11) or separate (R12): BOTH
//    produced corrupted f-gate ZW cols -> exploding c.  Root cause not
//    identified headless; zx_all store path stays as direct stores.
// Remaining known gaps (theory only): zx_all write stream (~74us, 123MB ZW,
// scattered 2B stores ~1.7TB/s effective); harness fill kernels (~40us,
// at HBM roofline, not ours); per-level small-kernel latency floor.
// ---------------------------------------------------------------------------

#define NN    4096
#define HH    300
#define KK    8
#define LVLS  12
#define KP    320
#define MTOT  49152   // 12*4096 rows in Xall
#define NW    1280    // ZW columns: [wf|wi|wo|wu]

typedef __bf16  bf16x8 __attribute__((ext_vector_type(8)));
typedef float   f32x4  __attribute__((ext_vector_type(4)));

#define GAS __attribute__((address_space(1)))
#define LAS __attribute__((address_space(3)))

__device__ __forceinline__ float sigmoidf_(float x) {
    return 1.0f / (1.0f + expf(-x));
}
__device__ __forceinline__ ushort f2bf(float f) {   // f32 -> bf16, RNE
    union { float f; uint32_t u; } v; v.f = f;
    return (ushort)((v.u + 0x7fffu + ((v.u >> 16) & 1u)) >> 16);
}
__device__ __forceinline__ float bf2f(ushort u) {
    union { uint32_t u; float f; } v; v.u = ((uint32_t)u) << 16;
    return v.f;
}

// ---------------------------------------------------------------------------
// pack (blocks [0,3527)) + stage X' (blocks [3527, 11207)).
// Layouts (all k-chunk-major = [k/8][cols][8], coalesced staging):
//   W4  [40][1280][8]   rows: 0-319 wf, 320-639 wi, 640-959 wo, 960-1279 wu
//   Uf' [40][320][8]
//   WzU [3][40][320][8] u_i / u_o / u_u
//   Xall'[40][49152][8]
//   BZ[3][320]=b_w+b_u (i,o,u), Bwf[320], BUF[320]
//   H'  [40][4096][8]: zero the k-pad elems (k>=300) once here.
// ---------------------------------------------------------------------------
__global__ __launch_bounds__(256)
void pack_and_stage(
    const float* __restrict__ wi, const float* __restrict__ bwi,
    const float* __restrict__ ui, const float* __restrict__ bui,
    const float* __restrict__ wf, const float* __restrict__ bwf,
    const float* __restrict__ uf, const float* __restrict__ buf_,
    const float* __restrict__ wo, const float* __restrict__ bwo,
    const float* __restrict__ uo, const float* __restrict__ buo,
    const float* __restrict__ wu, const float* __restrict__ bwu,
    const float* __restrict__ uu, const float* __restrict__ buu,
    ushort* __restrict__ W4, ushort* __restrict__ Ufp, ushort* __restrict__ WzU,
    float* __restrict__ BZ, float* __restrict__ Bwf, float* __restrict__ BUF,
    ushort* __restrict__ Hk,
    const int* __restrict__ word_ids, const float* __restrict__ emb,
    ushort* __restrict__ X)
{
    const int b = blockIdx.x;
    if (b >= 3527) {                                     // ---- stage X' ----
        int idx = (b - 3527) * 256 + threadIdx.x;        // 40 * 49152
        int kb = idx / MTOT, row = idx % MTOT;
        const int k0 = kb * 8;
        ushort o[8];
        if (kb < 37) {
            const float4* p = reinterpret_cast<const float4*>(
                emb + (size_t)word_ids[row] * 300 + k0);
            float4 v0 = p[0], v1 = p[1];
            o[0] = f2bf(v0.x); o[1] = f2bf(v0.y); o[2] = f2bf(v0.z); o[3] = f2bf(v0.w);
            o[4] = f2bf(v1.x); o[5] = f2bf(v1.y); o[6] = f2bf(v1.z); o[7] = f2bf(v1.w);
        } else if (kb == 37) {
            const float4 v0 = *reinterpret_cast<const float4*>(
                emb + (size_t)word_ids[row] * 300 + k0);
            o[0] = f2bf(v0.x); o[1] = f2bf(v0.y); o[2] = f2bf(v0.z); o[3] = f2bf(v0.w);
            o[4] = o[5] = o[6] = o[7] = 0;
        } else {
            o[0] = o[1] = o[2] = o[3] = o[4] = o[5] = o[6] = o[7] = 0;
        }
        ushort* dst = X + ((size_t)kb * MTOT + row) * 8;
        ushort4 a; a.x = o[0]; a.y = o[1]; a.z = o[2]; a.w = o[3];
        ushort4 c; c.x = o[4]; c.y = o[5]; c.z = o[6]; c.w = o[7];
        *reinterpret_cast<ushort4*>(dst)     = a;
        *reinterpret_cast<ushort4*>(dst + 4) = c;
        return;
    }
    int t = b * 256 + threadIdx.x;                       // ---- pack part ----
    if (t < 409600) {                                    // W4 [40][1280][8]
        int gate = t / 102400, rem = t % 102400;
        int r = rem / 320, k = rem % 320;
        const float* W = (gate == 0) ? wf : (gate == 1) ? wi
                       : (gate == 2) ? wo : wu;
        float v = (r < 300 && k < 300) ? W[r * 300 + k] : 0.f;
        W4[((size_t)(k >> 3) * NW + gate * 320 + r) * 8 + (k & 7)] = f2bf(v);
    } else if (t < 512000) {                             // Uf' [40][320][8]
        int x = t - 409600, r = x / 320, k = x % 320;
        Ufp[((size_t)(k >> 3) * KP + r) * 8 + (k & 7)] =
            f2bf((r < 300 && k < 300) ? uf[r * 300 + k] : 0.f);
    } else if (t < 819200) {                             // WzU [3][40][320][8]
        int x = t - 512000;
        int g = x / 102400, rem = x % 102400;
        int r = rem / 320, k = rem % 320;
        const float* U = (g == 0) ? ui : (g == 1) ? uo : uu;
        WzU[(((size_t)g * 40 + (k >> 3)) * KP + r) * 8 + (k & 7)] =
            f2bf((r < 300 && k < 300) ? U[r * 300 + k] : 0.f);
    } else if (t < 820160) {                             // BZ [3][320]
        int x = t - 819200, g = x / KP, r = x % KP;
        const float* bw = (g == 0) ? bwi : (g == 1) ? bwo : bwu;
        const float* bu = (g == 0) ? bui : (g == 1) ? buo : buu;
        BZ[x] = (r < 300) ? bw[r] + bu[r] : 0.f;
    } else if (t < 820480) {                             // Bwf
        int r = t - 820160;
        Bwf[r] = (r < 300) ? bwf[r] : 0.f;
    } else if (t < 820800) {                             // BUF
        int r = t - 820480;
        BUF[r] = (r < 300) ? buf_[r] : 0.f;
    } else if (t < 902720) {                             // H' k-pads -> 0
        int x = t - 820800;                              // 4096 * 20
        int row = x / 20, pe = x % 20;
        int k = 300 + pe;
        Hk[((size_t)(k >> 3) * NN + row) * 8 + (k & 7)] = 0;
    }
}

// ---------------------------------------------------------------------------
// ZW = X_all @ W4^T (+b_wf on cols<320) -> bf16 [49152][1280].
// Grid 3840 (384 m x 10 n), 256 thr, 128x128 tile (m97 structure: 16 MFMA
// per 8 ds_reads), BK=32, 10-step dbuf, counted vmcnt(4).  LDS 32 KB ->
// 4 blocks/CU.  Cols 0-319 = WXF (reduce); 320+g*320 = X-half of gate g.
// Direct per-fragment stores (LDS-staged variants R11/R12 both corrupted
// the output -- do not retry without disasm access).
// ---------------------------------------------------------------------------
__global__ __launch_bounds__(256)
void zx_all_kernel(const ushort* __restrict__ Xp, const ushort* __restrict__ W4,
                   const float* __restrict__ Bwf, ushort* __restrict__ ZW)
{
    __shared__ __attribute__((aligned(16))) ushort As[2][4][128][8];  // 16 KB
    __shared__ __attribute__((aligned(16))) ushort Bs[2][4][128][8];  // 16 KB

    const int b  = blockIdx.x;
    const int bj = (b % 8) * 480 + b / 8;         // bijective (3840 % 8 == 0)
    const int m0 = (bj / 10) * 128, n0 = (bj % 10) * 128;

    const int t = threadIdx.x, l = t & 63, w = t >> 6;
    const int m_off = (w >> 1) * 64, n_off = (w & 1) * 64;
    const int kq = l >> 4, lr = l & 15;

    f32x4 acc[4][4] = {};

    auto STAGE = [&](int buf, int s) {
        #pragma unroll
        for (int c = 0; c < 2; ++c) {             // A: 512 slots, 2/thread
            const int slot = t + 256 * c;
            const int kb = slot >> 7, row = slot & 127;
            const ushort* src = Xp + ((size_t)(s * 4 + kb) * MTOT + m0 + row) * 8;
            __builtin_amdgcn_global_load_lds((const GAS void*)src,
                (LAS void*)&As[buf][kb][row][0], 16, 0, 0);
        }
        #pragma unroll
        for (int c = 0; c < 2; ++c) {             // B: 512 slots, 2/thread
            const int slot = t + 256 * c;
            const int kb = slot >> 7, row = slot & 127;
            const ushort* src = W4 + ((size_t)(s * 4 + kb) * NW + n0 + row) * 8;
            __builtin_amdgcn_global_load_lds((const GAS void*)src,
                (LAS void*)&Bs[buf][kb][row][0], 16, 0, 0);
        }
    };
    auto COMPUTE = [&](int buf) {
        bf16x8 af[4], bfr[4];
        #pragma unroll
        for (int mi = 0; mi < 4; ++mi)
            af[mi] = *reinterpret_cast<const bf16x8*>(
                &As[buf][kq][m_off + mi * 16 + lr][0]);
        #pragma unroll
        for (int ni = 0; ni < 4; ++ni)
            bfr[ni] = *reinterpret_cast<const bf16x8*>(
                &Bs[buf][kq][n_off + ni * 16 + lr][0]);
        #pragma unroll
        for (int mi = 0; mi < 4; ++mi)
            #pragma unroll
            for (int ni = 0; ni < 4; ++ni)
                acc[mi][ni] = __builtin_amdgcn_mfma_f32_16x16x32_bf16(
                    af[mi], bfr[ni], acc[mi][ni], 0, 0, 0);
    };

    STAGE(0, 0);
    #pragma unroll
    for (int s = 0; s < 9; ++s) {
        STAGE((s + 1) & 1, s + 1);                // 4 loads in flight
        asm volatile("s_waitcnt vmcnt(4)" ::: "memory");
        __builtin_amdgcn_s_barrier();
        COMPUTE(s & 1);
        __builtin_amdgcn_s_barrier();
    }
    asm volatile("s_waitcnt vmcnt(0)" ::: "memory");
    __builtin_amdgcn_s_barrier();
    COMPUTE(1);                                   // step 9 -> buf 1

    const int col = l & 15, r0 = (l >> 4) * 4;
    #pragma unroll
    for (int mi = 0; mi < 4; ++mi) {
        #pragma unroll
        for (int ni = 0; ni < 4; ++ni) {
            const int gn = n0 + n_off + ni * 16 + col;
            const float bb = (gn < 320) ? Bwf[gn] : 0.f;
            #pragma unroll
            for (int r = 0; r < 4; ++r) {
                const int gm = m0 + m_off + mi * 16 + r0 + r;
                ZW[(size_t)gm * NW + gn] = f2bf(acc[mi][ni][r] + bb);
            }
        }
    }
}

// ---------------------------------------------------------------------------
// FP = H @ u_f^T + b_uf -> bf16 [4096][320] row-major.  Coalesced staged
// dbuf GEMM: A = H' k-major (written by zgemm), B = Uf' k-major.
// Grid 640 (64 m x 10 j), 256 thr, tile 64x32, BK=64, 5 steps, vmcnt(3).
// ---------------------------------------------------------------------------
__global__ __launch_bounds__(256)
void fp_kernel(const ushort* __restrict__ Hk, const ushort* __restrict__ Ufp,
               const float* __restrict__ BUFb, ushort* __restrict__ FP)
{
    __shared__ __attribute__((aligned(16))) ushort As[2][8][64][8];   // 16 KB
    __shared__ __attribute__((aligned(16))) ushort Bs[2][8][32][8];   //  8 KB

    const int b  = blockIdx.x;
    const int bj = (b % 8) * 80 + b / 8;          // bijective (640 % 8 == 0)
    const int m0 = (bj / 10) * 64, j0 = (bj % 10) * 32;

    const int t = threadIdx.x, w = t >> 6, l = t & 63;
    const int kq = l >> 4, lr = l & 15;
    const int m_off = (w >> 1) * 32, j_off = (w & 1) * 16;

    f32x4 acc[2] = {};

    auto STAGE = [&](int buf, int s) {
        #pragma unroll
        for (int c = 0; c < 2; ++c) {             // A: 512 slots, 2/thread
            const int slot = t + 256 * c;
            const int kb = slot >> 6, row = slot & 63;
            const ushort* src = Hk + ((size_t)(s * 8 + kb) * NN + m0 + row) * 8;
            __builtin_amdgcn_global_load_lds((const GAS void*)src,
                (LAS void*)&As[buf][kb][row][0], 16, 0, 0);
        }
        {                                         // B: 256 slots, 1/thread
            const int kb = t >> 5, row = t & 31;
            const ushort* src = Ufp + ((size_t)(s * 8 + kb) * KP + j0 + row) * 8;
            __builtin_amdgcn_global_load_lds((const GAS void*)src,
                (LAS void*)&Bs[buf][kb][row][0], 16, 0, 0);
        }
    };
    auto COMPUTE = [&](int buf) {
        #pragma unroll
        for (int kk = 0; kk < 2; ++kk) {
            const int kc = kk * 4 + kq;
            bf16x8 af[2], bf;
            #pragma unroll
            for (int mi = 0; mi < 2; ++mi)
                af[mi] = *reinterpret_cast<const bf16x8*>(
                    &As[buf][kc][m_off + mi * 16 + lr][0]);
            bf = *reinterpret_cast<const bf16x8*>(
                    &Bs[buf][kc][j_off + lr][0]);
            #pragma unroll
            for (int mi = 0; mi < 2; ++mi)
                acc[mi] = __builtin_amdgcn_mfma_f32_16x16x32_bf16(
                    af[mi], bf, acc[mi], 0, 0, 0);
        }
    };

    STAGE(0, 0);
    #pragma unroll
    for (int s = 0; s < 4; ++s) {
        STAGE((s + 1) & 1, s + 1);                // 3 loads in flight
        asm volatile("s_waitcnt vmcnt(3)" ::: "memory");
        __builtin_amdgcn_s_barrier();
        COMPUTE(s & 1);
        __builtin_amdgcn_s_barrier();
    }
    asm volatile("s_waitcnt vmcnt(0)" ::: "memory");
    __builtin_amdgcn_s_barrier();
    COMPUTE(0);                                   // step 4 -> buf 0

    const int col = l & 15, r0 = (l >> 4) * 4;
    const int gn = j0 + j_off + col;
    if (gn < 300) {
        const float bb = BUFb[gn];
        #pragma unroll
        for (int mi = 0; mi < 2; ++mi)
            #pragma unroll
            for (int r = 0; r < 4; ++r)
                FP[(size_t)(m0 + m_off + mi * 16 + r0 + r) * KP + gn] =
                    f2bf(acc[mi][r] + bb);
    }
}

// ---------------------------------------------------------------------------
// Child gather + masked sums.  4 nodes/block, branchless prefetched loads.
// WXF = ZW cols 0-319 (stride NW).  HT written k-chunk-major + pads zeroed.
// ---------------------------------------------------------------------------
__global__ __launch_bounds__(320)
void reduce_kernel(const ushort* __restrict__ Hbf, const float* __restrict__ Cst,
                   const ushort* __restrict__ FP, const ushort* __restrict__ ZWlev,
                   const int* __restrict__ cidx, const float* __restrict__ cmask,
                   ushort* __restrict__ HTp, float* __restrict__ SC)
{
    const int x = threadIdx.x;          // 0..79
    const int ty = threadIdx.y;         // 0..3
    const int n = blockIdx.x * 4 + ty;
    __shared__ int   ch[4][KK];
    __shared__ float mk[4][KK];
    if (x < KK) {
        ch[ty][x] = cidx[n * KK + x];
        mk[ty][x] = cmask[n * KK + x];
    }
    __syncthreads();
    if (x >= 75) {                      // zero HT' k-pad chunks
        ushort4 z; z.x = z.y = z.z = z.w = 0;
        const int pi = x - 75;          // (37,4),(38,0),(38,4),(39,0),(39,4)
        const int kb = 37 + ((pi + 1) >> 1);
        const int off = ((pi & 1) ^ 1) * 4;
        *reinterpret_cast<ushort4*>(
            HTp + ((size_t)kb * NN + n) * 8 + off) = z;
        return;
    }
    const int h = x * 4;

    ushort4 hu[KK]; ushort4 fu[KK]; float4 cv[KK];
    #pragma unroll
    for (int k = 0; k < KK; ++k) {
        const size_t cr = (size_t)ch[ty][k];
        hu[k] = *reinterpret_cast<const ushort4*>(&Hbf[cr * KP + h]);
        fu[k] = *reinterpret_cast<const ushort4*>(&FP [cr * KP + h]);
        cv[k] = *reinterpret_cast<const float4*>(&Cst[cr * HH + h]);
    }

    ushort4 wxu = *reinterpret_cast<const ushort4*>(&ZWlev[(size_t)n * NW + h]);
    const float wx0 = bf2f(wxu.x), wx1 = bf2f(wxu.y),
                wx2 = bf2f(wxu.z), wx3 = bf2f(wxu.w);
    float ht0 = 0.f, ht1 = 0.f, ht2 = 0.f, ht3 = 0.f;
    float sc0 = 0.f, sc1 = 0.f, sc2 = 0.f, sc3 = 0.f;

    #pragma unroll
    for (int k = 0; k < KK; ++k) {
        const float m = mk[ty][k];
        if (m != 0.f) {
            ht0 += m * bf2f(hu[k].x); ht1 += m * bf2f(hu[k].y);
            ht2 += m * bf2f(hu[k].z); ht3 += m * bf2f(hu[k].w);
            sc0 += m * sigmoidf_(wx0 + bf2f(fu[k].x)) * cv[k].x;
            sc1 += m * sigmoidf_(wx1 + bf2f(fu[k].y)) * cv[k].y;
            sc2 += m * sigmoidf_(wx2 + bf2f(fu[k].z)) * cv[k].z;
            sc3 += m * sigmoidf_(wx3 + bf2f(fu[k].w)) * cv[k].w;
        }
    }
    ushort4 ho; ho.x = f2bf(ht0); ho.y = f2bf(ht1); ho.z = f2bf(ht2); ho.w = f2bf(ht3);
    *reinterpret_cast<ushort4*>(
        HTp + ((size_t)(x >> 1) * NN + n) * 8 + (x & 1) * 4) = ho;
    float4 so; so.x = sc0; so.y = sc1; so.z = sc2; so.w = sc3;
    *reinterpret_cast<float4*>(&SC[(size_t)n * KP + h]) = so;
}

// ---------------------------------------------------------------------------
// zgemm: HT-half gates GEMM (K=320, 5 steps) + X-half addend from ZW +
// fused cell epilogue.  A = HT' k-major, B = WzU k-major.  Tile 64r x 32j x
// 3 gates; grid 640, 256 thr; dbuf, vmcnt(5).  Writes C, H row-major (for
// reduce gather) and H' k-major (for next level's fp staging).
// ---------------------------------------------------------------------------
__global__ __launch_bounds__(256)
void zgemm(const ushort* __restrict__ HTp, const ushort* __restrict__ WzU,
           const float* __restrict__ BZ, const float* __restrict__ SC,
           const ushort* __restrict__ ZXlev,
           float* __restrict__ cdst, ushort* __restrict__ Hb,
           ushort* __restrict__ Hk, float* __restrict__ hdst)
{
    __shared__ __attribute__((aligned(16))) ushort As[2][8][64][8];    // 16 KB
    __shared__ __attribute__((aligned(16))) ushort Bs[2][3][8][32][8]; // 24 KB

    const int b  = blockIdx.x;
    const int bj = (b % 8) * 80 + b / 8;          // bijective (640 % 8 == 0)
    const int m0 = (bj / 10) * 64, j0 = (bj % 10) * 32;

    const int t = threadIdx.x, w = t >> 6, l = t & 63;
    const int kq = l >> 4, lr = l & 15;
    const int m_off = (w >> 1) * 32, j_off = (w & 1) * 16;

    f32x4 acc[3][2] = {};

    auto STAGE = [&](int buf, int s) {
        #pragma unroll
        for (int c = 0; c < 2; ++c) {             // A: 512 slots, 2/thread
            const int slot = t + 256 * c;
            const int kb = slot >> 6, row = slot & 63;
            const ushort* src = HTp + ((size_t)(s * 8 + kb) * NN + m0 + row) * 8;
            __builtin_amdgcn_global_load_lds((const GAS void*)src,
                (LAS void*)&As[buf][kb][row][0], 16, 0, 0);
        }
        #pragma unroll
        for (int c = 0; c < 3; ++c) {             // B: 768 slots, 3/thread
            const int slot = t + 256 * c;
            const int g = slot >> 8, rem = slot & 255;
            const int kb = rem >> 5, row = rem & 31;
            const ushort* src = WzU +
                (((size_t)g * 40 + s * 8 + kb) * KP + j0 + row) * 8;
            __builtin_amdgcn_global_load_lds((const GAS void*)src,
                (LAS void*)&Bs[buf][g][kb][row][0], 16, 0, 0);
        }
    };
    auto COMPUTE = [&](int buf) {
        #pragma unroll
        for (int kk = 0; kk < 2; ++kk) {
            const int kc = kk * 4 + kq;
            bf16x8 af[2], bfr[3];
            #pragma unroll
            for (int mi = 0; mi < 2; ++mi)
                af[mi] = *reinterpret_cast<const bf16x8*>(
                    &As[buf][kc][m_off + mi * 16 + lr][0]);
            #pragma unroll
            for (int g = 0; g < 3; ++g)
                bfr[g] = *reinterpret_cast<const bf16x8*>(
                    &Bs[buf][g][kc][j_off + lr][0]);
            #pragma unroll
            for (int g = 0; g < 3; ++g)
                #pragma unroll
                for (int mi = 0; mi < 2; ++mi)
                    acc[g][mi] = __builtin_amdgcn_mfma_f32_16x16x32_bf16(
                        af[mi], bfr[g], acc[g][mi], 0, 0, 0);
        }
    };

    STAGE(0, 0);
    #pragma unroll
    for (int s = 0; s < 4; ++s) {
        STAGE((s + 1) & 1, s + 1);                // 5 loads in flight
        asm volatile("s_waitcnt vmcnt(5)" ::: "memory");
        __builtin_amdgcn_s_barrier();
        COMPUTE(s & 1);
        __builtin_amdgcn_s_barrier();
    }
    asm volatile("s_waitcnt vmcnt(0)" ::: "memory");
    __builtin_amdgcn_s_barrier();
    COMPUTE(0);                                   // step 4 -> buf 0

    // ---- epilogue: + X-half (ZW) + bias -> cell update ------------------
    const int col = l & 15, r0 = (l >> 4) * 4;
    const int gn = j0 + j_off + col;
    if (gn < 300) {
        const float bi_ = BZ[gn], bo_ = BZ[KP + gn], bu_ = BZ[2 * KP + gn];
        #pragma unroll
        for (int mi = 0; mi < 2; ++mi) {
            #pragma unroll
            for (int r = 0; r < 4; ++r) {
                const int gm = m0 + m_off + mi * 16 + r0 + r;
                const size_t zb = (size_t)gm * NW + 320 + gn;
                const float zi = bf2f(ZXlev[zb]);
                const float zo = bf2f(ZXlev[zb + 320]);
                const float zu = bf2f(ZXlev[zb + 640]);
                const float sc = SC[(size_t)gm * KP + gn];
                const float ig = sigmoidf_(acc[0][mi][r] + zi + bi_);
                const float og = sigmoidf_(acc[1][mi][r] + zo + bo_);
                const float ug = tanhf   (acc[2][mi][r] + zu + bu_);
                const float c  = ig * ug + sc;
                const float hv = og * tanhf(c);
                cdst[(size_t)gm * HH + gn] = c;
                const ushort hb = f2bf(hv);
                Hb[(size_t)gm * KP + gn] = hb;
                Hk[((size_t)(gn >> 3) * NN + gm) * 8 + (gn & 7)] = hb;
                if (hdst) hdst[(size_t)gm * HH + gn] = hv;
            }
        }
    }
}

// ---------------------------------------------------------------------------
extern "C" void kernel_launch(void* const* d_in, const int* in_sizes, int n_in,
                              void* d_out, int out_size, void* d_ws, size_t ws_size,
                              hipStream_t stream)
{
    const int*   word_ids   = (const int*)  d_in[0];
    const int*   child_idx  = (const int*)  d_in[1];
    const float* child_mask = (const float*)d_in[2];
    const float* emb        = (const float*)d_in[3];
    const float* w_i  = (const float*)d_in[4];  const float* b_wi = (const float*)d_in[5];
    const float* u_i  = (const float*)d_in[6];  const float* b_ui = (const float*)d_in[7];
    const float* w_f  = (const float*)d_in[8];  const float* b_wf = (const float*)d_in[9];
    const float* u_f  = (const float*)d_in[10]; const float* b_uf = (const float*)d_in[11];
    const float* w_o  = (const float*)d_in[12]; const float* b_wo = (const float*)d_in[13];
    const float* u_o  = (const float*)d_in[14]; const float* b_uo = (const float*)d_in[15];
    const float* w_u  = (const float*)d_in[16]; const float* b_wu = (const float*)d_in[17];
    const float* u_u  = (const float*)d_in[18]; const float* b_uu = (const float*)d_in[19];

    uint8_t* ws = (uint8_t*)d_ws;
    size_t off = 0;
    auto alloc = [&](size_t bytes) {
        uint8_t* p = ws + off;
        off += (bytes + 255) & ~(size_t)255;
        return p;
    };
    ushort* W4    = (ushort*)alloc((size_t)40 * NW * 8 * 2);      // k-major
    ushort* Ufp   = (ushort*)alloc((size_t)40 * KP * 8 * 2);      // k-major
    ushort* WzU   = (ushort*)alloc((size_t)3 * 40 * KP * 8 * 2);  // k-major
    ushort* Xall  = (ushort*)alloc((size_t)40 * MTOT * 8 * 2);    // k-major
    ushort* ZW    = (ushort*)alloc((size_t)MTOT * NW * 2);        // row-major
    ushort* FPbf  = (ushort*)alloc((size_t)NN * KP * 2);          // row-major
    ushort* HTp   = (ushort*)alloc((size_t)40 * NN * 8 * 2);      // k-major
    ushort* Hbf   = (ushort*)alloc((size_t)NN * KP * 2);          // row-major
    ushort* Hk    = (ushort*)alloc((size_t)40 * NN * 8 * 2);      // k-major
    float*  SCb   = (float*) alloc((size_t)NN * KP * 4);
    float*  C0    = (float*) alloc((size_t)NN * HH * 4);
    float*  BZ    = (float*) alloc(3 * KP * 4);
    float*  Bwf   = (float*) alloc(KP * 4);
    float*  BUFb  = (float*) alloc(KP * 4);

    pack_and_stage<<<11207, 256, 0, stream>>>(
        w_i, b_wi, u_i, b_ui, w_f, b_wf, u_f, b_uf,
        w_o, b_wo, u_o, b_uo, w_u, b_wu, u_u, b_uu,
        W4, Ufp, WzU, BZ, Bwf, BUFb, Hk,
        word_ids, emb, Xall);
    zx_all_kernel<<<3840, 256, 0, stream>>>(Xall, W4, Bwf, ZW);

    float* h_final = (float*)d_out;
    float* c_final = (float*)d_out + (size_t)NN * HH;

    for (int lev = 0; lev < LVLS; ++lev) {
        const int*    cidx  = child_idx  + (size_t)lev * NN * KK;
        const float*  cmask = child_mask + (size_t)lev * NN * KK;
        const ushort* ZWlev = ZW + (size_t)lev * NN * NW;
        const bool last = (lev == LVLS - 1);
        float* cdst = last ? c_final : C0;
        float* hdst = last ? h_final : nullptr;

        if (lev > 0)
            fp_kernel<<<640, 256, 0, stream>>>(Hk, Ufp, BUFb, FPbf);
        reduce_kernel<<<1024, dim3(80, 4), 0, stream>>>(
            Hbf, C0, FPbf, ZWlev, cidx, cmask, HTp, SCb);
        zgemm<<<640, 256, 0, stream>>>(
            HTp, WzU, BZ, SCb, ZWlev, cdst, Hbf, Hk, hdst);
    }
}